// Round 3
// baseline (878.927 us; speedup 1.0000x reference)
//
#include <hip/hip_runtime.h>
#include <hip/hip_bf16.h>
#include <math.h>

#define DD 512
#define EPSF 1e-8f
#define BM 128
#define BN 128
#define BK 32
#define FBIG 3.402823466e+38f
#define NPART 2048

typedef __bf16 bf16_t;
typedef __bf16 bf16x4_t __attribute__((ext_vector_type(4)));
typedef __bf16 bf16x8_t __attribute__((ext_vector_type(8)));
typedef float f32x4 __attribute__((ext_vector_type(4)));

__device__ inline float bf2f(unsigned short u) {
    return __uint_as_float(((unsigned int)u) << 16);
}

// ---------------- W fp32 -> bf16 (native [j][k] layout) ----------------
__global__ void k_convW(const float* __restrict__ W, bf16_t* __restrict__ Wb) {
    int i = blockIdx.x * blockDim.x + threadIdx.x;
    float4 v = ((const float4*)W)[i];
    bf16x4_t o;
    o[0] = (bf16_t)v.x; o[1] = (bf16_t)v.y; o[2] = (bf16_t)v.z; o[3] = (bf16_t)v.w;
    ((bf16x4_t*)Wb)[i] = o;
}

// ---------------- partial column sums + optional z->bf16 conversion ----------------
template<bool CONV>
__global__ void k_colsum(const float* __restrict__ z, bf16_t* __restrict__ zb,
                         float* __restrict__ part, int N, int rpb) {
    int t = threadIdx.x;                 // 256
    int b = blockIdx.x;                  // NPART
    int col4 = t & 127, sub = t >> 7;
    int r0 = b * rpb, r1 = min(r0 + rpb, N);
    const float4* z4 = (const float4*)z;
    float4 acc = make_float4(0.f, 0.f, 0.f, 0.f);
    #pragma unroll 4
    for (int r = r0 + sub; r < r1; r += 2) {
        float4 v = z4[(size_t)r * 128 + col4];
        if (CONV) {
            bf16x4_t o;
            o[0] = (bf16_t)v.x; o[1] = (bf16_t)v.y; o[2] = (bf16_t)v.z; o[3] = (bf16_t)v.w;
            ((bf16x4_t*)zb)[(size_t)r * 128 + col4] = o;
        }
        acc.x += v.x; acc.y += v.y; acc.z += v.z; acc.w += v.w;
    }
    __shared__ float4 sm[128];
    if (sub == 1) sm[col4] = acc;
    __syncthreads();
    if (sub == 0) {
        float4 o = sm[col4];
        acc.x += o.x; acc.y += o.y; acc.z += o.z; acc.w += o.w;
        ((float4*)(part + (size_t)b * DD))[col4] = acc;
    }
}

// reduce NPART partial vectors -> one [512] vector; one block per column
__global__ void k_reduceP(const float* __restrict__ part, float* __restrict__ outv, float scale) {
    __shared__ float sm[256];
    int j = blockIdx.x;
    int t = threadIdx.x;
    float s = 0.f;
    #pragma unroll
    for (int p = 0; p < NPART / 256; ++p) s += part[(size_t)(p * 256 + t) * DD + j];
    sm[t] = s;
    __syncthreads();
    for (int st = 128; st > 0; st >>= 1) {
        if (t < st) sm[t] += sm[t + st];
        __syncthreads();
    }
    if (t == 0) outv[j] = sm[0] * scale;
}

// ---------------- FUSED: d2 + online softmax + weighted vector accumulation ----------------
__global__ __launch_bounds__(256, 4) void k_d2w(
    const float* __restrict__ z, const float* __restrict__ cbar,
    float* __restrict__ part, float* __restrict__ mpart,
    float* __restrict__ spart, int N)
{
    __shared__ float4 cs[128];
    __shared__ float4 vsm[4][128];
    __shared__ float wm[4], wsv[4];
    int t = threadIdx.x;
    int lane = t & 63, wv = t >> 6;
    int l15 = lane & 15, r4 = lane >> 4;
    if (t < 128) cs[t] = ((const float4*)cbar)[t];
    __syncthreads();

    int gw = (blockIdx.x * 256 + t) >> 6;
    int nw = (gridDim.x * 256) >> 6;
    float m = FBIG, s = 0.f;
    float4 acc[8];
    #pragma unroll
    for (int q = 0; q < 8; ++q) acc[q] = make_float4(0.f, 0.f, 0.f, 0.f);

    for (int r = gw * 4 + r4; r < N; r += nw * 4) {
        const float4* zr = (const float4*)(z + (size_t)r * DD);
        float4 vv[8];
        float sum = 0.f;
        #pragma unroll
        for (int q = 0; q < 8; ++q) {
            float4 v = zr[q * 16 + l15];
            float4 c = cs[q * 16 + l15];
            vv[q] = v;
            float d;
            d = v.x - c.x; sum += d * d;
            d = v.y - c.y; sum += d * d;
            d = v.z - c.z; sum += d * d;
            d = v.w - c.w; sum += d * d;
        }
        #pragma unroll
        for (int off = 1; off < 16; off <<= 1) sum += __shfl_xor(sum, off, 64);
        float w;
        if (sum < m) {
            float f = __expf(-2.0f * (m - sum));
            s *= f;
            #pragma unroll
            for (int q = 0; q < 8; ++q) {
                acc[q].x *= f; acc[q].y *= f; acc[q].z *= f; acc[q].w *= f;
            }
            m = sum;
            w = 1.0f;
        } else {
            w = __expf(-2.0f * (sum - m));
        }
        s += w;
        #pragma unroll
        for (int q = 0; q < 8; ++q) {
            acc[q].x += w * vv[q].x; acc[q].y += w * vv[q].y;
            acc[q].z += w * vv[q].z; acc[q].w += w * vv[q].w;
        }
    }

    float mw = fminf(m, __shfl_xor(m, 16, 64));
    mw = fminf(mw, __shfl_xor(mw, 32, 64));
    float f = __expf(-2.0f * (m - mw));
    s *= f;
    #pragma unroll
    for (int q = 0; q < 8; ++q) {
        acc[q].x *= f; acc[q].y *= f; acc[q].z *= f; acc[q].w *= f;
    }
    #pragma unroll
    for (int off = 16; off < 64; off <<= 1) {
        s += __shfl_xor(s, off, 64);
        #pragma unroll
        for (int q = 0; q < 8; ++q) {
            acc[q].x += __shfl_xor(acc[q].x, off, 64);
            acc[q].y += __shfl_xor(acc[q].y, off, 64);
            acc[q].z += __shfl_xor(acc[q].z, off, 64);
            acc[q].w += __shfl_xor(acc[q].w, off, 64);
        }
    }
    if (lane < 16) {
        #pragma unroll
        for (int q = 0; q < 8; ++q) vsm[wv][q * 16 + l15] = acc[q];
        if (lane == 0) { wm[wv] = mw; wsv[wv] = s; }
    }
    __syncthreads();
    if (t < 128) {
        float M = fminf(fminf(wm[0], wm[1]), fminf(wm[2], wm[3]));
        float4 o = make_float4(0.f, 0.f, 0.f, 0.f);
        #pragma unroll
        for (int w2 = 0; w2 < 4; ++w2) {
            float fw = __expf(-2.0f * (wm[w2] - M));
            float4 a = vsm[w2][t];
            o.x += fw * a.x; o.y += fw * a.y; o.z += fw * a.z; o.w += fw * a.w;
        }
        ((float4*)(part + (size_t)blockIdx.x * DD))[t] = o;
        if (t == 0) {
            float S = 0.f;
            #pragma unroll
            for (int w2 = 0; w2 < 4; ++w2) S += wsv[w2] * __expf(-2.0f * (wm[w2] - M));
            mpart[blockIdx.x] = M;
            spart[blockIdx.x] = S;
        }
    }
}

// combine NPART (m,s) partials -> per-partial weight scale e^{-2(m_b-M)}/S
__global__ void k_combine2(const float* __restrict__ mpart, const float* __restrict__ spart,
                           float* __restrict__ wscale) {
    __shared__ float smm[256], sms[256];
    int t = threadIdx.x;
    float M = FBIG;
    for (int i = t; i < NPART; i += 256) M = fminf(M, mpart[i]);
    smm[t] = M;
    __syncthreads();
    for (int st = 128; st > 0; st >>= 1) {
        if (t < st) smm[t] = fminf(smm[t], smm[t + st]);
        __syncthreads();
    }
    M = smm[0];
    float S = 0.f;
    for (int i = t; i < NPART; i += 256) S += spart[i] * __expf(-2.0f * (mpart[i] - M));
    sms[t] = S;
    __syncthreads();
    for (int st = 128; st > 0; st >>= 1) {
        if (t < st) sms[t] += sms[t + st];
        __syncthreads();
    }
    float inv = 1.0f / sms[0];
    for (int i = t; i < NPART; i += 256) wscale[i] = __expf(-2.0f * (mpart[i] - M)) * inv;
}

// reduce NPART weighted partial vectors -> cvec
__global__ void k_reducePW(const float* __restrict__ part, const float* __restrict__ wscale,
                           float* __restrict__ outv) {
    __shared__ float sm[256];
    int j = blockIdx.x, t = threadIdx.x;
    float s = 0.f;
    #pragma unroll
    for (int p = 0; p < NPART / 256; ++p) {
        int b = p * 256 + t;
        s += part[(size_t)b * DD + j] * wscale[b];
    }
    sm[t] = s;
    __syncthreads();
    for (int st = 128; st > 0; st >>= 1) {
        if (t < st) sm[t] += sm[t + st];
        __syncthreads();
    }
    if (t == 0) outv[j] = sm[0];
}

// ---------------- cnorm_inv ----------------
__global__ void k_cnorm(const float* __restrict__ cvec, float* __restrict__ outp) {
    __shared__ float sm[512];
    float v = cvec[threadIdx.x];
    sm[threadIdx.x] = v * v;
    __syncthreads();
    for (int st = 256; st > 0; st >>= 1) {
        if (threadIdx.x < st) sm[threadIdx.x] += sm[threadIdx.x + st];
        __syncthreads();
    }
    if (threadIdx.x == 0) outp[0] = 1.0f / fmaxf(sqrtf(sm[0]), EPSF);
}

// ======================= 256x256 / BK=64 / 8-wave GEMM, half-piece pipeline ===============
// LDS pieces: A[buf][mhalf][128 rows][64k], B[buf][nhalf][128 cols][64k] (16 KB each).
// Each wave reads exactly one A-piece (wr) and one B-piece (wc>>1); pieces die at tile end.
// Tile T+1 is burst-staged into buf cur^1 (idle all tile) at tile TOP -> no mid-tile
// barrier, no lgkmcnt(0) drain; compiler interleaves ds_read/MFMA with counted lgkmcnt.
// One vmcnt(0)+barrier per tile; the waited loads were issued a full tile earlier.
// T2 swizzle: LDS[row][x] = G[row][x ^ ((row&7)<<4)], applied source-side.
__global__ __launch_bounds__(512, 2) void k_gemm256(
    const bf16_t* __restrict__ zb, const bf16_t* __restrict__ Wb,
    const float* __restrict__ bvec, const float* __restrict__ cvec,
    float* __restrict__ sqp, float* __restrict__ dtp, int N, int npad)
{
    __shared__ bf16_t As[2 * 2 * 128 * 64];   // 64 KB: [buf][mhalf][row][k]
    __shared__ bf16_t Bs[2 * 2 * 128 * 64];   // 64 KB: [buf][nhalf][col][k]

    const int t    = threadIdx.x;         // 0..511
    const int lane = t & 63;
    const int wid  = t >> 6;              // 0..7
    const int wr   = wid >> 2;            // 0..1  (row half)
    const int wc   = wid & 3;             // 0..3  (col quarter)
    const int quad = lane >> 4;
    const int l15  = lane & 15;

    // XCD-aware bijective swizzle (m204)
    const int nwg = gridDim.x * gridDim.y;
    const int lid = blockIdx.y * gridDim.x + blockIdx.x;
    const int q8  = nwg >> 3, r8 = nwg & 7;
    const int xcd = lid & 7, idx = lid >> 3;
    const int wg  = (xcd < r8 ? xcd * (q8 + 1) : r8 * (q8 + 1) + (xcd - r8) * q8) + idx;
    const int cb     = wg & 1;            // col block (0..1)
    const int row0   = (wg >> 1) * 256;

    // staging: thread t covers global row (base + t>>3), 16 B at byte
    // ((t&7)*16) ^ (((t>>3)&7)<<4)  (inverse swizzle on source, linear LDS dest)
    const int tr = t >> 3;                // 0..63
    const int bo = ((t & 7) * 16) ^ ((tr & 7) << 4);
    const char* apt = (const char*)zb + (size_t)(row0 + tr) * (DD * 2) + bo;
    const char* bpt = (const char*)Wb + (size_t)(cb * 256 + tr) * (DD * 2) + bo;
    const int ldsw = __builtin_amdgcn_readfirstlane(wid * 1024);

// stage all 4 pieces (A-mh0, A-mh1, B-nh0, B-nh1) of tile kt into buffer `buf`
#define STAGEALL(buf, kt) do {                                                              \
    _Pragma("unroll")                                                                       \
    for (int h_ = 0; h_ < 2; ++h_) {                                                        \
        _Pragma("unroll")                                                                   \
        for (int j_ = 0; j_ < 2; ++j_) {                                                    \
            __builtin_amdgcn_global_load_lds(                                               \
                (const __attribute__((address_space(1))) unsigned int*)(const void*)        \
                    (apt + (size_t)(h_ * 128 + j_ * 64) * 1024 + (kt) * 128),               \
                (__attribute__((address_space(3))) unsigned int*)(void*)                    \
                    ((char*)As + (buf) * 32768 + h_ * 16384 + j_ * 8192 + ldsw), 16, 0, 0); \
            __builtin_amdgcn_global_load_lds(                                               \
                (const __attribute__((address_space(1))) unsigned int*)(const void*)        \
                    (bpt + (size_t)(h_ * 128 + j_ * 64) * 1024 + (kt) * 128),               \
                (__attribute__((address_space(3))) unsigned int*)(void*)                    \
                    ((char*)Bs + (buf) * 32768 + h_ * 16384 + j_ * 8192 + ldsw), 16, 0, 0); \
        }                                                                                   \
    }                                                                                       \
} while (0)

    // fragment read bases: wave's A piece = wr, B piece = wc>>1
    const char* abase = (const char*)As + wr * 16384 + l15 * 128;
    const char* bbase = (const char*)Bs + (wc >> 1) * 16384 + ((wc & 1) * 64 + l15) * 128;
    const int kq = quad * 16;                       // pre-swizzle k-byte
    const int sw = (l15 & 7) << 4;                  // row swizzle bits

    f32x4 acc[8][4];
    #pragma unroll
    for (int m = 0; m < 8; ++m)
        #pragma unroll
        for (int n = 0; n < 4; ++n) acc[m][n] = (f32x4){0.f, 0.f, 0.f, 0.f};

    // prologue: stage tile 0 into buf 0
    STAGEALL(0, 0);
    asm volatile("s_waitcnt vmcnt(0)" ::: "memory");
    __builtin_amdgcn_sched_barrier(0);
    __builtin_amdgcn_s_barrier();
    __builtin_amdgcn_sched_barrier(0);

    #pragma unroll
    for (int kt = 0; kt < 8; ++kt) {
        const int cur = kt & 1;
        if (kt < 7) STAGEALL(cur ^ 1, kt + 1);      // idle buffer: race-free, lands ~1 tile later
        __builtin_amdgcn_sched_barrier(0);          // pin stage issue before compute
        __builtin_amdgcn_s_setprio(1);
        #pragma unroll
        for (int s = 0; s < 2; ++s) {
            const int kb = (s * 64 + kq) ^ sw;      // swizzled byte within 128-B row
            bf16x8_t afr[8], bfr[4];
            #pragma unroll
            for (int m = 0; m < 8; ++m)
                afr[m] = *(const bf16x8_t*)(abase + cur * 32768 + m * 2048 + kb);
            #pragma unroll
            for (int n = 0; n < 4; ++n)
                bfr[n] = *(const bf16x8_t*)(bbase + cur * 32768 + n * 2048 + kb);
            #pragma unroll
            for (int m = 0; m < 8; ++m)
                #pragma unroll
                for (int n = 0; n < 4; ++n)
                    acc[m][n] = __builtin_amdgcn_mfma_f32_16x16x32_bf16(
                        afr[m], bfr[n], acc[m][n], 0, 0, 0);
        }
        __builtin_amdgcn_s_setprio(0);
        if (kt < 7) { asm volatile("s_waitcnt vmcnt(0)" ::: "memory"); }  // tile kt+1 landed
        __builtin_amdgcn_sched_barrier(0);
        __builtin_amdgcn_s_barrier();               // all waves done with buf[cur]
        __builtin_amdgcn_sched_barrier(0);
    }
#undef STAGEALL

    // ---- epilogue: x = acc + b[col]; per-row partial sq / dot(c) over this 256-col block ----
    float* psq = (float*)As;
    float* pdt = (float*)((char*)As + 16384);
    float bc[4], cc[4];
    #pragma unroll
    for (int n = 0; n < 4; ++n) {
        int col = cb * 256 + wc * 64 + n * 16 + l15;
        bc[n] = bvec[col];
        cc[n] = cvec[col];
    }
    #pragma unroll
    for (int m = 0; m < 8; ++m) {
        #pragma unroll
        for (int rg = 0; rg < 4; ++rg) {
            float sq = 0.f, dt = 0.f;
            #pragma unroll
            for (int n = 0; n < 4; ++n) {
                float x = acc[m][n][rg] + bc[n];
                sq += x * x;
                dt += x * cc[n];
            }
            sq += __shfl_xor(sq, 1, 64); dt += __shfl_xor(dt, 1, 64);
            sq += __shfl_xor(sq, 2, 64); dt += __shfl_xor(dt, 2, 64);
            if ((l15 & 3) == 0) {
                int row = wr * 128 + m * 16 + quad * 4 + rg;
                int slot = wc * 4 + (l15 >> 2);
                psq[row * 16 + slot] = sq;
                pdt[row * 16 + slot] = dt;
            }
        }
    }
    __syncthreads();
    if (t < 256) {
        int r = row0 + t;
        if (r < N) {
            const float4* p4 = (const float4*)(psq + t * 16);
            const float4* d4 = (const float4*)(pdt + t * 16);
            float sq = 0.f, dt = 0.f;
            #pragma unroll
            for (int i = 0; i < 4; ++i) {
                float4 a = p4[i], b2 = d4[i];
                sq += a.x + a.y + a.z + a.w;
                dt += b2.x + b2.y + b2.z + b2.w;
            }
            sqp[(size_t)cb * npad + r] = sq;
            dtp[(size_t)cb * npad + r] = dt;
        }
    }
}

// ---------------- fallback MFMA GEMM (fp32 A path, 128x128, proven) ----------------
__global__ __launch_bounds__(256, 4) void k_gemm_fb(
    const float* __restrict__ z, const bf16_t* __restrict__ Wb,
    const float* __restrict__ bvec, const float* __restrict__ cvec,
    float* __restrict__ sqp, float* __restrict__ dtp, int N, int npad)
{
    __shared__ bf16_t Asl[BM * BK];
    __shared__ bf16_t Bsl[BN * BK];
    __shared__ float psq[BM][8];
    __shared__ float pdt[BM][8];

    const int t    = threadIdx.x;
    const int lane = t & 63;
    const int wv   = t >> 6;
    const int wrr  = wv >> 1;
    const int wcc  = wv & 1;
    const int quad = lane >> 4;
    const int l15  = lane & 15;
    const int cbx  = blockIdx.x;
    const int row0 = blockIdx.y * BM;

    const bf16_t* bp = Wb + (size_t)(cbx * BN + (t >> 2)) * DD + (t & 3) * 8;
    const int arow = t >> 1;
    const int ah   = t & 1;
    int rowe = row0 + arow; if (rowe >= N) rowe = N - 1;
    const float4* zp4 = (const float4*)(z + (size_t)rowe * DD + ah * 16);

    f32x4 acc[4][4];
    #pragma unroll
    for (int a = 0; a < 4; ++a)
        #pragma unroll
        for (int b = 0; b < 4; ++b) acc[a][b] = (f32x4){0.f, 0.f, 0.f, 0.f};

    float4 v0 = zp4[0], v1 = zp4[1], v2 = zp4[2], v3 = zp4[3];

    for (int kc = 0; kc < DD; kc += BK) {
        if (kc) __syncthreads();
        #pragma unroll
        for (int q = 0; q < 2; ++q) {
            int ldsoff = __builtin_amdgcn_readfirstlane(q * 4096 + wv * 1024);
            __builtin_amdgcn_global_load_lds(
                (const __attribute__((address_space(1))) unsigned int*)(const void*)(bp + (size_t)q * 64 * DD + kc),
                (__attribute__((address_space(3))) unsigned int*)(void*)((char*)Bsl + ldsoff),
                16, 0, 0);
        }
        bf16x8_t lo, hi;
        lo[0]=(bf16_t)v0.x; lo[1]=(bf16_t)v0.y; lo[2]=(bf16_t)v0.z; lo[3]=(bf16_t)v0.w;
        lo[4]=(bf16_t)v1.x; lo[5]=(bf16_t)v1.y; lo[6]=(bf16_t)v1.z; lo[7]=(bf16_t)v1.w;
        hi[0]=(bf16_t)v2.x; hi[1]=(bf16_t)v2.y; hi[2]=(bf16_t)v2.z; hi[3]=(bf16_t)v2.w;
        hi[4]=(bf16_t)v3.x; hi[5]=(bf16_t)v3.y; hi[6]=(bf16_t)v3.z; hi[7]=(bf16_t)v3.w;
        *(bf16x8_t*)(Asl + arow * BK + ah * 16)     = lo;
        *(bf16x8_t*)(Asl + arow * BK + ah * 16 + 8) = hi;
        __syncthreads();
        if (kc + BK < DD) {
            int kf = (kc + BK) >> 2;
            v0 = zp4[kf]; v1 = zp4[kf + 1]; v2 = zp4[kf + 2]; v3 = zp4[kf + 3];
        }
        bf16x8_t af[4];
        #pragma unroll
        for (int rt = 0; rt < 4; ++rt)
            af[rt] = *(const bf16x8_t*)(Asl + (wrr * 64 + rt * 16 + l15) * BK + quad * 8);
        #pragma unroll
        for (int ct = 0; ct < 4; ++ct) {
            bf16x8_t bfv = *(const bf16x8_t*)(Bsl + (wcc * 64 + ct * 16 + l15) * BK + quad * 8);
            #pragma unroll
            for (int rt = 0; rt < 4; ++rt)
                acc[rt][ct] = __builtin_amdgcn_mfma_f32_16x16x32_bf16(af[rt], bfv, acc[rt][ct], 0, 0, 0);
        }
    }

    float bc[4], cc[4];
    #pragma unroll
    for (int ct = 0; ct < 4; ++ct) {
        int col = cbx * BN + wcc * 64 + ct * 16 + l15;
        bc[ct] = bvec[col];
        cc[ct] = cvec[col];
    }
    #pragma unroll
    for (int rt = 0; rt < 4; ++rt) {
        #pragma unroll
        for (int rg = 0; rg < 4; ++rg) {
            float sq = 0.f, dt = 0.f;
            #pragma unroll
            for (int ct = 0; ct < 4; ++ct) {
                float x = acc[rt][ct][rg] + bc[ct];
                sq += x * x;
                dt += x * cc[ct];
            }
            sq += __shfl_xor(sq, 1, 64); dt += __shfl_xor(dt, 1, 64);
            sq += __shfl_xor(sq, 2, 64); dt += __shfl_xor(dt, 2, 64);
            if ((l15 & 3) == 0) {
                int rl = wrr * 64 + rt * 16 + quad * 4 + rg;
                psq[rl][wcc * 4 + (l15 >> 2)] = sq;
                pdt[rl][wcc * 4 + (l15 >> 2)] = dt;
            }
        }
    }
    __syncthreads();
    if (t < BM) {
        int r = row0 + t;
        if (r < N) {
            float sq = 0.f, dt = 0.f;
            #pragma unroll
            for (int i = 0; i < 8; ++i) { sq += psq[t][i]; dt += pdt[t][i]; }
            sqp[(size_t)cbx * npad + r] = sq;
            dtp[(size_t)cbx * npad + r] = dt;
        }
    }
}

// ---------------- combine NCB col-block partials -> dist ----------------
template<int NCB>
__global__ void k_final(const float* __restrict__ sqp, const float* __restrict__ dtp,
                        const float* __restrict__ cninv, float* __restrict__ out,
                        int N, int npad) {
    int r = blockIdx.x * blockDim.x + threadIdx.x;
    if (r < N) {
        float sq = 0.f, dt = 0.f;
        #pragma unroll
        for (int i = 0; i < NCB; ++i) {
            sq += sqp[(size_t)i * npad + r];
            dt += dtp[(size_t)i * npad + r];
        }
        out[r] = 1.0f - dt * cninv[0] / fmaxf(sqrtf(sq), EPSF);
    }
}

extern "C" void kernel_launch(void* const* d_in, const int* in_sizes, int n_in,
                              void* d_out, int out_size, void* d_ws, size_t ws_size,
                              hipStream_t stream)
{
    const float* z = (const float*)d_in[0];
    const float* W = (const float*)d_in[1];
    const float* b = (const float*)d_in[2];
    float* out = (float*)d_out;
    int N = in_sizes[0] / DD;
    int npad = ((N + 255) / 256) * 256;    // 256-aligned for the 256^2 GEMM

    float* ws = (float*)d_ws;
    size_t off = 0;
    float* part   = ws + off; off += (size_t)NPART * DD;
    float* cbar   = ws + off; off += DD;
    float* mpart  = ws + off; off += NPART;
    float* spart  = ws + off; off += NPART;
    float* wscale = ws + off; off += NPART;
    float* cvec   = ws + off; off += DD;
    float* cninv  = ws + off; off += 1;
    off = (off + 3) & ~(size_t)3;
    float* sqp    = ws + off; off += (size_t)4 * npad;
    float* dtp    = ws + off; off += (size_t)4 * npad;
    bf16_t* Wb    = (bf16_t*)(ws + off); off += (size_t)DD * DD / 2;
    bf16_t* zb    = (bf16_t*)(ws + off);
    size_t need_bytes = (off + (size_t)npad * DD / 2) * sizeof(float);
    const bool use_zb = ws_size >= need_bytes;

    int rpb = (N + NPART - 1) / NPART;

    k_convW<<<256, 256, 0, stream>>>(W, Wb);
    if (use_zb) k_colsum<true ><<<NPART, 256, 0, stream>>>(z, zb, part, N, rpb);
    else        k_colsum<false><<<NPART, 256, 0, stream>>>(z, zb, part, N, rpb);
    k_reduceP<<<DD, 256, 0, stream>>>(part, cbar, 1.0f / (float)N);
    k_d2w<<<NPART, 256, 0, stream>>>(z, cbar, part, mpart, spart, N);
    k_combine2<<<1, 256, 0, stream>>>(mpart, spart, wscale);
    k_reducePW<<<DD, 256, 0, stream>>>(part, wscale, cvec);
    k_cnorm<<<1, DD, 0, stream>>>(cvec, cninv);
    if (use_zb) {
        dim3 grid(2, npad / 256);
        k_gemm256<<<grid, 512, 0, stream>>>(zb, Wb, b, cvec, sqp, dtp, N, npad);
        k_final<2><<<(N + 255) / 256, 256, 0, stream>>>(sqp, dtp, cninv, out, N, npad);
    } else {
        dim3 grid(4, npad / BM);
        k_gemm_fb<<<grid, 256, 0, stream>>>(z, Wb, b, cvec, sqp, dtp, N, npad);
        k_final<4><<<(N + 255) / 256, 256, 0, stream>>>(sqp, dtp, cninv, out, N, npad);
    }
}